// Round 1
// baseline (849.244 us; speedup 1.0000x reference)
//
#include <hip/hip_runtime.h>

#define HALF (1 << 23)   // 2^23 dim-index pairs
#define BATCH 4

// Kernel 1: compute per-batch 2x2 complex U matrices into ws (coeff-major):
// ws[c*4 + b] for c in {m00r,m00i,m01r,m01i,m10r,m10i,m11r,m11i}
__global__ void prep_mats(const float* __restrict__ thetas, float* __restrict__ ws) {
    int b = threadIdx.x;
    if (b < BATCH) {
        float phi   = thetas[0 * BATCH + b];
        float theta = thetas[1 * BATCH + b];
        float omega = thetas[2 * BATCH + b];
        float ct = cosf(theta * 0.5f), st = sinf(theta * 0.5f);
        float ap = (phi + omega) * 0.5f;
        float am = (phi - omega) * 0.5f;
        float cp = cosf(ap), sp = sinf(ap);
        float cm = cosf(am), sm = sinf(am);
        // t_plus  = cp - i*sp,  t_minus = cm - i*sm
        // m00 = ct * t_plus        = ct*cp - i*ct*sp
        ws[0 * BATCH + b] =  ct * cp;
        ws[1 * BATCH + b] = -ct * sp;
        // m01 = -st * conj(t_minus) = -st*(cm + i*sm)
        ws[2 * BATCH + b] = -st * cm;
        ws[3 * BATCH + b] = -st * sm;
        // m10 = st * t_minus        = st*cm - i*st*sm
        ws[4 * BATCH + b] =  st * cm;
        ws[5 * BATCH + b] = -st * sm;
        // m11 = ct * conj(t_plus)   = ct*cp + i*ct*sp
        ws[6 * BATCH + b] =  ct * cp;
        ws[7 * BATCH + b] =  ct * sp;
    }
}

// Kernel 2: one thread per lower-half dim index. B=4 batch values per dim
// index are contiguous -> one float4 per (array, dim).
__global__ __launch_bounds__(256) void apply_gate(
        const float* __restrict__ state_real,
        const float* __restrict__ state_imag,
        const float* __restrict__ mats,
        float* __restrict__ out) {
    int i = blockIdx.x * blockDim.x + threadIdx.x;  // dim index in [0, HALF)

    const float4* sr4 = (const float4*)state_real;
    const float4* si4 = (const float4*)state_imag;
    float4* out4 = (float4*)out;

    float4 v0r = sr4[i];
    float4 v1r = sr4[i + HALF];
    float4 v0i = si4[i];
    float4 v1i = si4[i + HALF];

    const float* p0r = (const float*)&v0r;
    const float* p0i = (const float*)&v0i;
    const float* p1r = (const float*)&v1r;
    const float* p1i = (const float*)&v1i;

    float4 o0r, o0i, o1r, o1i;
    float* q0r = (float*)&o0r;
    float* q0i = (float*)&o0i;
    float* q1r = (float*)&o1r;
    float* q1i = (float*)&o1i;

#pragma unroll
    for (int k = 0; k < 4; ++k) {
        // uniform (wave-constant) matrix coefficient loads -> scalar/L2 hits
        float m00r = mats[0 * 4 + k], m00i = mats[1 * 4 + k];
        float m01r = mats[2 * 4 + k], m01i = mats[3 * 4 + k];
        float m10r = mats[4 * 4 + k], m10i = mats[5 * 4 + k];
        float m11r = mats[6 * 4 + k], m11i = mats[7 * 4 + k];

        float ar = p0r[k], ai = p0i[k];   // s0 (lower half)
        float br = p1r[k], bi = p1i[k];   // s1 (upper half)

        // out0 = m00*s0 + m01*s1
        q0r[k] = m00r * ar - m00i * ai + m01r * br - m01i * bi;
        q0i[k] = m00r * ai + m00i * ar + m01r * bi + m01i * br;
        // out1 = m10*s0 + m11*s1
        q1r[k] = m10r * ar - m10i * ai + m11r * br - m11i * bi;
        q1i[k] = m10r * ai + m10i * ar + m11r * bi + m11i * br;
    }

    // Output layout: (2, DIM, B) f32. Real plane = [0, DIM*B), imag plane
    // follows. In float4 units the imag plane starts at 2*HALF.
    out4[i]            = o0r;  // real, lower half
    out4[i + HALF]     = o1r;  // real, upper half
    out4[i + 2 * HALF] = o0i;  // imag, lower half
    out4[i + 3 * HALF] = o1i;  // imag, upper half
}

extern "C" void kernel_launch(void* const* d_in, const int* in_sizes, int n_in,
                              void* d_out, int out_size, void* d_ws, size_t ws_size,
                              hipStream_t stream) {
    const float* state_real = (const float*)d_in[0];
    const float* state_imag = (const float*)d_in[1];
    const float* thetas     = (const float*)d_in[2];
    float* out = (float*)d_out;
    float* ws  = (float*)d_ws;

    prep_mats<<<1, 64, 0, stream>>>(thetas, ws);
    apply_gate<<<HALF / 256, 256, 0, stream>>>(state_real, state_imag, ws, out);
}